// Round 9
// baseline (238.011 us; speedup 1.0000x reference)
//
#include <hip/hip_runtime.h>
#include <hip/hip_bf16.h>
#include <type_traits>

typedef __hip_bfloat16 bf16;
typedef __attribute__((ext_vector_type(8))) short bf16x8;
typedef __attribute__((ext_vector_type(4))) float f32x4;
typedef __attribute__((ext_vector_type(16))) float f32x16;

#define N_LOC 4096

__device__ __forceinline__ bf16 to_bf16(float f) { return __float2bfloat16(f); }

// async global->LDS DMA, 16B per lane; LDS dest = wave-uniform base + lane*16
__device__ __forceinline__ void dma16(const bf16* g, bf16* l) {
  __builtin_amdgcn_global_load_lds((const __attribute__((address_space(1))) unsigned int*)g,
                                   (__attribute__((address_space(3))) unsigned int*)l, 16, 0, 0);
}

// ---------------- prep: fused {f32->bf16 convert of Q,K,V,Wo} + {W transpose-pack} ----------------
__global__ __launch_bounds__(256) void prep(const float* __restrict__ Q, const float* __restrict__ K,
                                            const float* __restrict__ V, const float* __restrict__ Wo,
                                            bf16* __restrict__ Qb, bf16* __restrict__ Kb,
                                            bf16* __restrict__ Vb, bf16* __restrict__ Wob,
                                            const float* __restrict__ Wq, const float* __restrict__ Wk,
                                            const float* __restrict__ Wv,
                                            bf16* __restrict__ oq, bf16* __restrict__ ok,
                                            bf16* __restrict__ ov) {
  __shared__ float tile[64][65];
  if (blockIdx.x < 3328) {
    long i = ((long)blockIdx.x * 256 + threadIdx.x) * 8;
    const float* src;
    bf16* dst;
    long off;
    if (i < 2097152)      { src = Q;  dst = Qb;  off = i; }
    else if (i < 4194304) { src = K;  dst = Kb;  off = i - 2097152; }
    else if (i < 6291456) { src = V;  dst = Vb;  off = i - 4194304; }
    else                  { src = Wo; dst = Wob; off = i - 6291456; }
    float4 a = *(const float4*)&src[off];
    float4 b = *(const float4*)&src[off + 4];
    union { bf16 h[8]; bf16x8 v; } u;
    u.h[0] = to_bf16(a.x); u.h[1] = to_bf16(a.y); u.h[2] = to_bf16(a.z); u.h[3] = to_bf16(a.w);
    u.h[4] = to_bf16(b.x); u.h[5] = to_bf16(b.y); u.h[6] = to_bf16(b.z); u.h[7] = to_bf16(b.w);
    *(bf16x8*)&dst[off] = u.v;
  } else {
    int pid = blockIdx.x - 3328;            // 0..383  (old dims: x 8, y 16, z 3)
    int z = pid >> 7;
    int rem = pid & 127;
    int xx = rem & 7, y = rem >> 3;
    const float* W = (z == 0) ? Wq : (z == 1) ? Wk : Wv;
    bf16* out = (z == 0) ? oq : (z == 1) ? ok : ov;
    int DH = (z == 2) ? 256 : 128;
    int nt = DH >> 6;
    if (y >= 4 * nt) return;
    int h = y / nt, tt = y - h * nt;
    int d0 = xx * 64, t0 = tt * 64;
    for (int i = threadIdx.x; i < 4096; i += 256) {
      int r = i >> 6, c = i & 63;
      tile[r][c] = W[((size_t)h * 512 + d0 + r) * DH + t0 + c];
    }
    __syncthreads();
    for (int i = threadIdx.x; i < 4096; i += 256) {
      int t = i >> 6, d = i & 63;
      out[((size_t)(h * DH + t0 + t)) * 512 + d0 + d] = to_bf16(tile[d][t]);
    }
  }
}

// ---------------- 128xBN GEMM body, double-buffered counted-vmcnt staging ----------------
// MODE 0: C bf16 [M][N]; MODE 1: C f32 [M][N]; MODE 2: C bf16 TRANSPOSED (vT[col][row], ld 4096)
template <int BN, int MODE, typename OutT>
__device__ __forceinline__ void gemm_body(const bf16* __restrict__ A, const bf16* __restrict__ Bt,
                                          OutT* __restrict__ C, int N, int K, int m0, int n0,
                                          bf16* sm) {
  constexpr int WN = BN / 2, JN = WN / 16, NB = BN / 32;
  int tid = threadIdx.x, lane = tid & 63, w = tid >> 6;
  int quad = lane >> 4, l16 = lane & 15;
  int wm = (w >> 1) * 64, wn = (w & 1) * WN;
  int srow = lane >> 3;            // row-within-8-group staged by this lane
  int sG = (lane & 7) ^ srow;      // source granule for stored position lane&7

  bf16* Asb[2] = { sm, sm + 8192 };
  bf16* Bsb[2] = { sm + 16384, sm + 16384 + BN * 64 };

  const bf16* ga[4];
  const bf16* gb[NB];
#pragma unroll
  for (int j = 0; j < 4; j++) ga[j] = A + (long)(m0 + (4 * j + w) * 8 + srow) * K + sG * 8;
#pragma unroll
  for (int j = 0; j < NB; j++) gb[j] = Bt + (long)(n0 + (4 * j + w) * 8 + srow) * K + sG * 8;

  auto stage = [&](int b) {
#pragma unroll
    for (int j = 0; j < 4; j++) { dma16(ga[j], &Asb[b][(4 * j + w) * 512]); ga[j] += 64; }
#pragma unroll
    for (int j = 0; j < NB; j++) { dma16(gb[j], &Bsb[b][(4 * j + w) * 512]); gb[j] += 64; }
  };

  f32x4 acc[4][JN] = {};
  stage(0);
  asm volatile("" ::: "memory");
  int cur = 0;
  const int NK = K >> 6;
  for (int s = 0; s < NK; ++s) {
    if (s + 1 < NK) {
      stage(cur ^ 1);
      if constexpr (NB == 4) asm volatile("s_waitcnt vmcnt(8)" ::: "memory");
      else                   asm volatile("s_waitcnt vmcnt(6)" ::: "memory");
    } else {
      asm volatile("s_waitcnt vmcnt(0)" ::: "memory");
    }
    __builtin_amdgcn_s_barrier();      // tile s landed for all waves
    asm volatile("" ::: "memory");
    const bf16* Ac = Asb[cur];
    const bf16* Bc = Bsb[cur];
#pragma unroll
    for (int kk = 0; kk < 2; kk++) {
      bf16x8 af[4], bfr[JN];
#pragma unroll
      for (int i = 0; i < 4; i++) {
        int r = wm + i * 16 + l16;
        af[i] = *(const bf16x8*)&Ac[r * 64 + (((kk * 4 + quad) ^ r) & 7) * 8];
      }
#pragma unroll
      for (int j = 0; j < JN; j++) {
        int r = wn + j * 16 + l16;
        bfr[j] = *(const bf16x8*)&Bc[r * 64 + (((kk * 4 + quad) ^ r) & 7) * 8];
      }
#pragma unroll
      for (int i = 0; i < 4; i++)
#pragma unroll
        for (int j = 0; j < JN; j++)
          acc[i][j] = __builtin_amdgcn_mfma_f32_16x16x32_bf16(af[i], bfr[j], acc[i][j], 0, 0, 0);
    }
    asm volatile("" ::: "memory");
    __builtin_amdgcn_s_barrier();      // buf cur free for next stage's overwrite
    asm volatile("" ::: "memory");
    cur ^= 1;
  }

  if constexpr (MODE == 2) {
    bf16* tp = sm;  // [128][136] bf16 = 34.8 KB (sm is 64 KB)
#pragma unroll
    for (int i = 0; i < 4; i++)
#pragma unroll
      for (int j = 0; j < JN; j++)
#pragma unroll
        for (int r = 0; r < 4; r++)
          tp[(wn + j * 16 + l16) * 136 + wm + i * 16 + quad * 4 + r] = to_bf16(acc[i][j][r]);
    __syncthreads();
#pragma unroll
    for (int it = 0; it < 8; ++it) {
      int idx = it * 256 + tid;
      int rown = idx >> 4, c8 = (idx & 15) * 8;
      *(bf16x8*)&C[(size_t)(n0 + rown) * 4096 + m0 + c8] = *(const bf16x8*)&tp[rown * 136 + c8];
    }
  } else {
#pragma unroll
    for (int i = 0; i < 4; i++)
#pragma unroll
      for (int j = 0; j < JN; j++)
#pragma unroll
        for (int r = 0; r < 4; r++) {
          long row = m0 + wm + i * 16 + quad * 4 + r;
          long col = n0 + wn + j * 16 + l16;
          if constexpr (MODE == 0)
            C[row * N + col] = to_bf16(acc[i][j][r]);
          else
            C[row * N + col] = acc[i][j][r];
        }
  }
}

// merged q/k/v projections, exact 512-block grid; z==2 writes vT directly (transposed epilogue)
__global__ __launch_bounds__(256) void proj_gemm(const bf16* __restrict__ QKVb,
                                                 const bf16* __restrict__ Wt,
                                                 bf16* __restrict__ qkout,
                                                 bf16* __restrict__ vTout) {
  __shared__ __align__(16) bf16 sm[4 * 128 * 64];   // 64 KB
  int bid = blockIdx.x;
  if (bid < 256) {
    int z = bid >> 7;                 // 0:q 1:k
    int t = bid & 127;
    int m0 = (t & 31) * 128, n0 = (t >> 5) * 128;
    gemm_body<128, 0, bf16>(QKVb + (size_t)z * 2097152, Wt + (size_t)z * 262144,
                            qkout + (size_t)z * 2097152, 512, 512, m0, n0, sm);
  } else {
    int t = bid - 256;                // 0..255 -> v projection, 4096x1024
    int m0 = (t & 31) * 128, n0 = (t >> 5) * 128;
    gemm_body<128, 2, bf16>(QKVb + (size_t)2 * 2097152, Wt + (size_t)2 * 262144,
                            vTout, 1024, 512, m0, n0, sm);
  }
}

// output projection: 128x64 tiles -> 256 blocks
__global__ __launch_bounds__(256) void out_gemm(const bf16* __restrict__ xin,
                                                const bf16* __restrict__ Wob,
                                                float* __restrict__ outp) {
  __shared__ __align__(16) bf16 sm[2 * 128 * 64 + 2 * 64 * 64];   // 48 KB
  gemm_body<64, 1, float>(xin, Wob, outp, 512, 1024, blockIdx.x * 128, blockIdx.y * 64, sm);
}

// ---------------- fused attention (R9: 32x32x16 MFMA, in-register P, RNE packing) ----------------
// qb,kb: [N][512]; vT: [1024][N]; x: [N][1024]
// Block = (head, dvh, q0): 128 q x 128 dv; 4 waves x 32 q; grid 256 = 1 block/CU, 64 KB LDS.
// Wave owns 32 q x ALL 64 keys x ALL 128 dv -> softmax + P wave-private.
// S^T = mfma_32x32x16(K-frag, Q-frag): D col=q=lane&31, row=key=(reg&3)+8*(reg>>2)+4*hi.
// R9 fix vs R8: P packs via RNE __float2bfloat16 (union), NOT inline-asm
// v_cvt_pk_bf16_f32 -- the hand-written cvt_pk's rounding bias (~0.2% low on every P,
// with L unbiased f32) produced the 4.65e-4 systematic error. PV B-frag still built by
// 2x v_permlane32_swap_b32 per 16-key chunk (exchange verified lane-by-lane).
// PV = mfma_32x32x16(V^T-frag, P-frag) accumulating O^T[dv][q]. L = per-lane f32 sum
// + one shfl_xor(32). Only per-tile sync: vmcnt(0) (pre-landed) + one s_barrier (dbuf).
__global__ __launch_bounds__(256, 2) void attn(const bf16* __restrict__ qb,
                                               const bf16* __restrict__ kb,
                                               const bf16* __restrict__ vT,
                                               bf16* __restrict__ x) {
  __shared__ __align__(16) bf16 kt[2][64 * 128];   // [key][dk] swizzled, 2x16 KB
  __shared__ __align__(16) bf16 vt[2][128 * 64];   // [dv-half][key] swizzled, 2x16 KB

  const int bid = blockIdx.x;                      // 256 blocks
  const int xcd = bid & 7;
  const int head = xcd & 3;                        // one (head,dvh) pair per XCD
  const int dvh = xcd >> 2;                        // dv half 0..1
  const int q0 = (bid >> 3) * 128;                 // 0..3968
  const int tid = threadIdx.x;
  const int lane = tid & 63, w = tid >> 6;         // w = 0..3
  const int l32 = lane & 31, hi = lane >> 5;
  const int qw = q0 + w * 32;                      // this wave's 32 q-rows

  // Q as 32x32x16 B-frags: n=l32 (q), k = hi*8 + j, per dk-16 chunk c (8 chunks)
  bf16x8 qfB[8];
  {
    const bf16* qrow = &qb[(size_t)(qw + l32) * 512 + head * 128];
#pragma unroll
    for (int c = 0; c < 8; c++) qfB[c] = *(const bf16x8*)&qrow[c * 16 + hi * 8];
  }

  f32x16 oacc[4] = {};         // O^T frags: [dv-tile d], col=q=l32, row=dv
  float Lp = 0.0f;             // partial softmax denom for q=l32 (this hi-half's keys)
  const float scale = 1.0f / 64.0f;  // 1/sqrt(4096)

  // staging pointers: each wave stages 4 kt-groups (4 key-rows x 128 dk) and
  // 4 vt-groups (8 dv-rows x 64 keys); XOR-swizzled source granules. (R7-proven.)
  const bf16* kpa[4];
  const bf16* vpa[4];
#pragma unroll
  for (int t2 = 0; t2 < 4; t2++) {
    int j = 4 * w + t2;
    {
      int r = 4 * j + (lane >> 4);
      int p = lane & 15;
      int G = (p & 8) | ((p ^ r) & 7);
      kpa[t2] = kb + (size_t)r * 512 + head * 128 + G * 8;
    }
    {
      int r = 8 * j + (lane >> 3);
      int p = lane & 7;
      int G = (p ^ r) & 7;
      vpa[t2] = vT + (size_t)(head * 256 + dvh * 128 + r) * 4096 + G * 8;
    }
  }
  auto STAGE = [&](int b) {
#pragma unroll
    for (int t2 = 0; t2 < 4; t2++) {
      dma16(kpa[t2], &kt[b][(4 * w + t2) * 512]); kpa[t2] += 64 * 512;
      dma16(vpa[t2], &vt[b][(4 * w + t2) * 512]); vpa[t2] += 64;
    }
  };

  STAGE(0);
  asm volatile("" ::: "memory");
  int cur = 0;

  for (int t = 0; t < 64; ++t) {
    // tile t's 8 DMAs were issued a full tile ago -> wait is ~free
    asm volatile("s_waitcnt vmcnt(0)" ::: "memory");
    __builtin_amdgcn_s_barrier();    // all waves: tile t landed AND tile t-1 reads done
    asm volatile("" ::: "memory");
    if (t < 63) STAGE(cur ^ 1);      // overwrites buffer last read at tile t-1 (safe)

    // ---- S^T = K @ Q^T : two 32-key tiles; lane holds q=l32, 16 keys each tile ----
    const bf16* ktc = kt[cur];
    f32x16 s0 = {}, s1 = {};
#pragma unroll
    for (int c = 0; c < 8; c++) {
      int G = c * 2 + hi;
      int p8 = (((G ^ l32) & 7) | (G & 8)) * 8;    // same low-3 XOR for row and row+32
      bf16x8 kf0 = *(const bf16x8*)&ktc[l32 * 128 + p8];
      bf16x8 kf1 = *(const bf16x8*)&ktc[(32 + l32) * 128 + p8];
      s0 = __builtin_amdgcn_mfma_f32_32x32x16_bf16(kf0, qfB[c], s0, 0, 0, 0);
      s1 = __builtin_amdgcn_mfma_f32_32x32x16_bf16(kf1, qfB[c], s1, 0, 0, 0);
    }

    // ---- exp + L + pack (RNE): reg pair (2i,2i+1) = keys ktile*32+2(i&1)+8*(i>>1)+4*hi ----
    unsigned pk[16];   // [ktile*8 + i]; PV chunk c uses pk[c*4 .. c*4+3]
#pragma unroll
    for (int i = 0; i < 8; i++) {
      float p0 = __expf(s0[2 * i] * scale), p1 = __expf(s0[2 * i + 1] * scale);
      float p2 = __expf(s1[2 * i] * scale), p3 = __expf(s1[2 * i + 1] * scale);
      Lp += (p0 + p1) + (p2 + p3);
      union { bf16 h[2]; unsigned u; } a0, a1;
      a0.h[0] = to_bf16(p0); a0.h[1] = to_bf16(p1);
      a1.h[0] = to_bf16(p2); a1.h[1] = to_bf16(p3);
      pk[i] = a0.u;
      pk[8 + i] = a1.u;
    }

    // ---- O^T += V^T @ P : per 16-key chunk, 2 permlane swaps build the B-frag ----
    const bf16* vtc = vt[cur];
#pragma unroll
    for (int c = 0; c < 4; c++) {
      unsigned w0 = pk[c * 4 + 0], w1 = pk[c * 4 + 1];
      unsigned w2 = pk[c * 4 + 2], w3 = pk[c * 4 + 3];
      asm("v_permlane32_swap_b32 %0, %1" : "+v"(w0), "+v"(w2));
      asm("v_permlane32_swap_b32 %0, %1" : "+v"(w1), "+v"(w3));
      union { unsigned u[4]; bf16x8 v; } pb;
      pb.u[0] = w0; pb.u[1] = w1; pb.u[2] = w2; pb.u[3] = w3;
      int G = c * 2 + hi;
#pragma unroll
      for (int d = 0; d < 4; d++) {
        int R = d * 32 + l32;
        bf16x8 vf = *(const bf16x8*)&vtc[R * 64 + ((G ^ R) & 7) * 8];
        oacc[d] = __builtin_amdgcn_mfma_f32_32x32x16_bf16(vf, pb.v, oacc[d], 0, 0, 0);
      }
    }
    cur ^= 1;
  }

  // ---- L: lane's 32 P-sums cover keys of its hi-half; partner has the rest ----
  float Lf = Lp + __shfl_xor(Lp, 32);
  float inv = 1.0f / Lf;

  // ---- normalize + store: lane q=l32; dv = d*32 + 2(i&1)+8*(i>>1)+4*hi (+1 pair) ----
  bf16* xrow = &x[(size_t)(qw + l32) * 1024 + head * 256 + dvh * 128];
#pragma unroll
  for (int d = 0; d < 4; d++)
#pragma unroll
    for (int i = 0; i < 8; i++) {
      int dvp = d * 32 + 2 * (i & 1) + 8 * (i >> 1) + 4 * hi;
      union { bf16 h[2]; unsigned u; } o2;
      o2.h[0] = to_bf16(oacc[d][2 * i] * inv);
      o2.h[1] = to_bf16(oacc[d][2 * i + 1] * inv);
      *(unsigned*)&xrow[dvp] = o2.u;
    }
}

// ---------------- launch ----------------
extern "C" void kernel_launch(void* const* d_in, const int* in_sizes, int n_in,
                              void* d_out, int out_size, void* d_ws, size_t ws_size,
                              hipStream_t stream) {
  const float* Q  = (const float*)d_in[0];
  const float* Km = (const float*)d_in[1];
  const float* V  = (const float*)d_in[2];
  const float* Wq = (const float*)d_in[3];
  const float* Wk = (const float*)d_in[4];
  const float* Wv = (const float*)d_in[5];
  const float* Wo = (const float*)d_in[6];
  float* out = (float*)d_out;

  bf16* ws  = (bf16*)d_ws;
  bf16* Qb  = ws;                 // 4096x512   (Qb,Kb,Vb contiguous)
  bf16* Kb  = Qb + 2097152;
  bf16* Vb  = Kb + 2097152;
  bf16* Wqt = Vb + 2097152;       // 512x512  (Wqt,Wkt,Wvt contiguous)
  bf16* Wkt = Wqt + 262144;
  bf16* Wvt = Wkt + 262144;       // 1024x512 (Bt)
  bf16* Wob = Wvt + 524288;       // 512x1024 (Bt = Wo as-is)
  bf16* qb  = Wob + 524288;       // 4096x512   (qb,kb contiguous)
  bf16* kb  = qb + 2097152;
  bf16* vT  = kb + 2097152;       // 1024x4096  (written directly by proj z==2)
  bf16* x   = vT + 4194304;       // 4096x1024

  prep<<<3712, 256, 0, stream>>>(Q, Km, V, Wo, Qb, Kb, Vb, Wob, Wq, Wk, Wv, Wqt, Wkt, Wvt);

  proj_gemm<<<512, 256, 0, stream>>>(Qb, Wqt, qb, vT);

  attn<<<256, 256, 0, stream>>>(qb, kb, vT, x);

  out_gemm<<<dim3(32, 8), 256, 0, stream>>>(x, Wob, out);
}

// Round 10
// 210.990 us; speedup vs baseline: 1.1281x; 1.1281x over previous
//
#include <hip/hip_runtime.h>
#include <hip/hip_bf16.h>
#include <type_traits>

typedef __hip_bfloat16 bf16;
typedef __attribute__((ext_vector_type(8))) short bf16x8;
typedef __attribute__((ext_vector_type(4))) float f32x4;

#define N_LOC 4096

__device__ __forceinline__ bf16 to_bf16(float f) { return __float2bfloat16(f); }

// async global->LDS DMA, 16B per lane; LDS dest = wave-uniform base + lane*16
__device__ __forceinline__ void dma16(const bf16* g, bf16* l) {
  __builtin_amdgcn_global_load_lds((const __attribute__((address_space(1))) unsigned int*)g,
                                   (__attribute__((address_space(3))) unsigned int*)l, 16, 0, 0);
}

// ---------------- prep: fused {f32->bf16 convert of Q,K,V,Wo} + {W transpose-pack} ----------------
__global__ __launch_bounds__(256) void prep(const float* __restrict__ Q, const float* __restrict__ K,
                                            const float* __restrict__ V, const float* __restrict__ Wo,
                                            bf16* __restrict__ Qb, bf16* __restrict__ Kb,
                                            bf16* __restrict__ Vb, bf16* __restrict__ Wob,
                                            const float* __restrict__ Wq, const float* __restrict__ Wk,
                                            const float* __restrict__ Wv,
                                            bf16* __restrict__ oq, bf16* __restrict__ ok,
                                            bf16* __restrict__ ov) {
  __shared__ float tile[64][65];
  if (blockIdx.x < 3328) {
    long i = ((long)blockIdx.x * 256 + threadIdx.x) * 8;
    const float* src;
    bf16* dst;
    long off;
    if (i < 2097152)      { src = Q;  dst = Qb;  off = i; }
    else if (i < 4194304) { src = K;  dst = Kb;  off = i - 2097152; }
    else if (i < 6291456) { src = V;  dst = Vb;  off = i - 4194304; }
    else                  { src = Wo; dst = Wob; off = i - 6291456; }
    float4 a = *(const float4*)&src[off];
    float4 b = *(const float4*)&src[off + 4];
    union { bf16 h[8]; bf16x8 v; } u;
    u.h[0] = to_bf16(a.x); u.h[1] = to_bf16(a.y); u.h[2] = to_bf16(a.z); u.h[3] = to_bf16(a.w);
    u.h[4] = to_bf16(b.x); u.h[5] = to_bf16(b.y); u.h[6] = to_bf16(b.z); u.h[7] = to_bf16(b.w);
    *(bf16x8*)&dst[off] = u.v;
  } else {
    int pid = blockIdx.x - 3328;            // 0..383  (old dims: x 8, y 16, z 3)
    int z = pid >> 7;
    int rem = pid & 127;
    int xx = rem & 7, y = rem >> 3;
    const float* W = (z == 0) ? Wq : (z == 1) ? Wk : Wv;
    bf16* out = (z == 0) ? oq : (z == 1) ? ok : ov;
    int DH = (z == 2) ? 256 : 128;
    int nt = DH >> 6;
    if (y >= 4 * nt) return;
    int h = y / nt, tt = y - h * nt;
    int d0 = xx * 64, t0 = tt * 64;
    for (int i = threadIdx.x; i < 4096; i += 256) {
      int r = i >> 6, c = i & 63;
      tile[r][c] = W[((size_t)h * 512 + d0 + r) * DH + t0 + c];
    }
    __syncthreads();
    for (int i = threadIdx.x; i < 4096; i += 256) {
      int t = i >> 6, d = i & 63;
      out[((size_t)(h * DH + t0 + t)) * 512 + d0 + d] = to_bf16(tile[d][t]);
    }
  }
}

// ---------------- 128xBN GEMM body, double-buffered counted-vmcnt staging ----------------
// MODE 0: C bf16 [M][N]; MODE 1: C f32 [M][N]; MODE 2: C bf16 TRANSPOSED (vT[col][row], ld 4096)
template <int BN, int MODE, typename OutT>
__device__ __forceinline__ void gemm_body(const bf16* __restrict__ A, const bf16* __restrict__ Bt,
                                          OutT* __restrict__ C, int N, int K, int m0, int n0,
                                          bf16* sm) {
  constexpr int WN = BN / 2, JN = WN / 16, NB = BN / 32;
  int tid = threadIdx.x, lane = tid & 63, w = tid >> 6;
  int quad = lane >> 4, l16 = lane & 15;
  int wm = (w >> 1) * 64, wn = (w & 1) * WN;
  int srow = lane >> 3;            // row-within-8-group staged by this lane
  int sG = (lane & 7) ^ srow;      // source granule for stored position lane&7

  bf16* Asb[2] = { sm, sm + 8192 };
  bf16* Bsb[2] = { sm + 16384, sm + 16384 + BN * 64 };

  const bf16* ga[4];
  const bf16* gb[NB];
#pragma unroll
  for (int j = 0; j < 4; j++) ga[j] = A + (long)(m0 + (4 * j + w) * 8 + srow) * K + sG * 8;
#pragma unroll
  for (int j = 0; j < NB; j++) gb[j] = Bt + (long)(n0 + (4 * j + w) * 8 + srow) * K + sG * 8;

  auto stage = [&](int b) {
#pragma unroll
    for (int j = 0; j < 4; j++) { dma16(ga[j], &Asb[b][(4 * j + w) * 512]); ga[j] += 64; }
#pragma unroll
    for (int j = 0; j < NB; j++) { dma16(gb[j], &Bsb[b][(4 * j + w) * 512]); gb[j] += 64; }
  };

  f32x4 acc[4][JN] = {};
  stage(0);
  asm volatile("" ::: "memory");
  int cur = 0;
  const int NK = K >> 6;
  for (int s = 0; s < NK; ++s) {
    if (s + 1 < NK) {
      stage(cur ^ 1);
      if constexpr (NB == 4) asm volatile("s_waitcnt vmcnt(8)" ::: "memory");
      else                   asm volatile("s_waitcnt vmcnt(6)" ::: "memory");
    } else {
      asm volatile("s_waitcnt vmcnt(0)" ::: "memory");
    }
    __builtin_amdgcn_s_barrier();      // tile s landed for all waves
    asm volatile("" ::: "memory");
    const bf16* Ac = Asb[cur];
    const bf16* Bc = Bsb[cur];
#pragma unroll
    for (int kk = 0; kk < 2; kk++) {
      bf16x8 af[4], bfr[JN];
#pragma unroll
      for (int i = 0; i < 4; i++) {
        int r = wm + i * 16 + l16;
        af[i] = *(const bf16x8*)&Ac[r * 64 + (((kk * 4 + quad) ^ r) & 7) * 8];
      }
#pragma unroll
      for (int j = 0; j < JN; j++) {
        int r = wn + j * 16 + l16;
        bfr[j] = *(const bf16x8*)&Bc[r * 64 + (((kk * 4 + quad) ^ r) & 7) * 8];
      }
#pragma unroll
      for (int i = 0; i < 4; i++)
#pragma unroll
        for (int j = 0; j < JN; j++)
          acc[i][j] = __builtin_amdgcn_mfma_f32_16x16x32_bf16(af[i], bfr[j], acc[i][j], 0, 0, 0);
    }
    asm volatile("" ::: "memory");
    __builtin_amdgcn_s_barrier();      // buf cur free for next stage's overwrite
    asm volatile("" ::: "memory");
    cur ^= 1;
  }

  if constexpr (MODE == 2) {
    bf16* tp = sm;  // [128][136] bf16 = 34.8 KB (sm is 64 KB)
#pragma unroll
    for (int i = 0; i < 4; i++)
#pragma unroll
      for (int j = 0; j < JN; j++)
#pragma unroll
        for (int r = 0; r < 4; r++)
          tp[(wn + j * 16 + l16) * 136 + wm + i * 16 + quad * 4 + r] = to_bf16(acc[i][j][r]);
    __syncthreads();
#pragma unroll
    for (int it = 0; it < 8; ++it) {
      int idx = it * 256 + tid;
      int rown = idx >> 4, c8 = (idx & 15) * 8;
      *(bf16x8*)&C[(size_t)(n0 + rown) * 4096 + m0 + c8] = *(const bf16x8*)&tp[rown * 136 + c8];
    }
  } else {
#pragma unroll
    for (int i = 0; i < 4; i++)
#pragma unroll
      for (int j = 0; j < JN; j++)
#pragma unroll
        for (int r = 0; r < 4; r++) {
          long row = m0 + wm + i * 16 + quad * 4 + r;
          long col = n0 + wn + j * 16 + l16;
          if constexpr (MODE == 0)
            C[row * N + col] = to_bf16(acc[i][j][r]);
          else
            C[row * N + col] = acc[i][j][r];
        }
  }
}

// merged q/k/v projections, exact 512-block grid; z==2 writes vT directly (transposed epilogue)
__global__ __launch_bounds__(256) void proj_gemm(const bf16* __restrict__ QKVb,
                                                 const bf16* __restrict__ Wt,
                                                 bf16* __restrict__ qkout,
                                                 bf16* __restrict__ vTout) {
  __shared__ __align__(16) bf16 sm[4 * 128 * 64];   // 64 KB
  int bid = blockIdx.x;
  if (bid < 256) {
    int z = bid >> 7;                 // 0:q 1:k
    int t = bid & 127;
    int m0 = (t & 31) * 128, n0 = (t >> 5) * 128;
    gemm_body<128, 0, bf16>(QKVb + (size_t)z * 2097152, Wt + (size_t)z * 262144,
                            qkout + (size_t)z * 2097152, 512, 512, m0, n0, sm);
  } else {
    int t = bid - 256;                // 0..255 -> v projection, 4096x1024
    int m0 = (t & 31) * 128, n0 = (t >> 5) * 128;
    gemm_body<128, 2, bf16>(QKVb + (size_t)2 * 2097152, Wt + (size_t)2 * 262144,
                            vTout, 1024, 512, m0, n0, sm);
  }
}

// output projection: 128x64 tiles -> 256 blocks
__global__ __launch_bounds__(256) void out_gemm(const bf16* __restrict__ xin,
                                                const bf16* __restrict__ Wob,
                                                float* __restrict__ outp) {
  __shared__ __align__(16) bf16 sm[2 * 128 * 64 + 2 * 64 * 64];   // 48 KB
  gemm_body<64, 1, float>(xin, Wob, outp, 512, 1024, blockIdx.x * 128, blockIdx.y * 64, sm);
}

// ---------------- fused attention (R10: R3 structure + merged S(t+1)||PV(t) phase) ----------------
// qb,kb: [N][512]; vT: [1024][N]; x: [N][1024]
// Block = (head, dvh, q0): 64 q x 128 dv; 8 waves (cd,g); grid 512 = 2 blocks/CU (73.5 KB LDS).
// R10 change vs R3: S runs ONE TILE AHEAD. Per iter: {load pf(t) -> regs; barrier;
// stage K(t+2),V(t+1); counted vmcnt; [S(t+1) MFMAs || PV(t) MFMAs] in one phase;
// exp(t+1)+pt-write; barrier}. 2 barriers/tile (was 3) and the two MFMA phases overlap
// within each wave. Buffer parity: kt read (t+1)%2 / written t%2; vt read t%2 / written
// (t+1)%2 (prior reader PV(t-1) is 2 barriers back); pt reads drained (lgkmcnt 0 +
// barrier) before overwrite. vmcnt: steady 4, t=62 -> 2, t=63 -> 0.
__global__ __launch_bounds__(512, 4) void attn(const bf16* __restrict__ qb,
                                               const bf16* __restrict__ kb,
                                               const bf16* __restrict__ vT,
                                               bf16* __restrict__ x) {
  __shared__ __align__(16) bf16 kt[2][64 * 128];   // [key][dk] swizzled, 2x16 KB
  __shared__ __align__(16) bf16 vt[2][128 * 64];   // [dv-half][key] swizzled, 2x16 KB
  __shared__ __align__(16) bf16 pt[64 * 72];       // [q][key], padded (9 KB)
  __shared__ float Lrow[64];

  const int bid = blockIdx.x;                      // 512 blocks
  const int xcd = bid & 7;
  const int head = xcd & 3;                        // one (head,dvh) pair per XCD
  const int dvh = xcd >> 2;                        // dv half 0..1
  const int q0 = (bid >> 3) * 64;                  // 0..4032
  const int tid = threadIdx.x;
  const int lane = tid & 63, w = tid >> 6;
  const int quad = lane >> 4, l16 = lane & 15;
  const int cd = w & 3;   // S: 16-key col tile; PV: 32-dv group
  const int g = w >> 2;   // q half

  // all-ones B-fragment: B[n][k] = (n==0) -> D[q][0] = sum_k P[q][k]
  bf16x8 onesf;
  {
    union { bf16 h[8]; bf16x8 v; } u;
    bf16 one = to_bf16(1.0f), zero = to_bf16(0.0f);
#pragma unroll
    for (int j = 0; j < 8; j++) u.h[j] = (l16 == 0) ? one : zero;
    onesf = u.v;
  }

  // preload q fragments (A-layout: m=l16, k=quad*8+j)
  bf16x8 qf[2][4];
#pragma unroll
  for (int i = 0; i < 2; i++) {
    const bf16* qrow = &qb[(size_t)(q0 + g * 32 + i * 16 + l16) * 512 + head * 128];
#pragma unroll
    for (int kk = 0; kk < 4; kk++) qf[i][kk] = *(const bf16x8*)&qrow[kk * 32 + quad * 8];
  }

  f32x4 oacc[2][2] = {};
  f32x4 oL[2] = {};
  const float scale = 1.0f / 64.0f;  // 1/sqrt(4096)

  // DMA source pointers (advance per staged tile). kt: 16 j-groups (4 key-rows x 128 dk);
  // vt: 16 j-groups (8 dv-rows x 64 keys). j = 2w+t2.
  const int j0 = 2 * w, j1 = 2 * w + 1;
  const bf16 *kp0, *kp1, *vp0, *vp1;
  {
    int r0 = 4 * j0 + (lane >> 4), r1 = 4 * j1 + (lane >> 4);
    int p = lane & 15;
    int G0 = (p & 8) | ((p ^ r0) & 7), G1 = (p & 8) | ((p ^ r1) & 7);
    kp0 = kb + (size_t)r0 * 512 + head * 128 + G0 * 8;
    kp1 = kb + (size_t)r1 * 512 + head * 128 + G1 * 8;
  }
  {
    int r0 = 8 * j0 + (lane >> 3), r1 = 8 * j1 + (lane >> 3);
    int p = lane & 7;
    int G0 = (p ^ r0) & 7, G1 = (p ^ r1) & 7;
    vp0 = vT + (size_t)(head * 256 + dvh * 128 + r0) * 4096 + G0 * 8;
    vp1 = vT + (size_t)(head * 256 + dvh * 128 + r1) * 4096 + G1 * 8;
  }

#define STAGE_K(b)                                      \
  do {                                                  \
    dma16(kp0, &kt[b][j0 * 512]);                       \
    dma16(kp1, &kt[b][j1 * 512]);                       \
    kp0 += 64 * 512; kp1 += 64 * 512;                   \
  } while (0)
#define STAGE_V(b)                                      \
  do {                                                  \
    dma16(vp0, &vt[b][j0 * 512]);                       \
    dma16(vp1, &vt[b][j1 * 512]);                       \
    vp0 += 64; vp1 += 64;                               \
  } while (0)

  // S-phase body: compute S for tile in kt[buf], exp, write pt
#define S_PHASE(buf)                                                            \
  do {                                                                          \
    const bf16* ktc = kt[buf];                                                  \
    f32x4 sacc[2] = {};                                                         \
    _Pragma("unroll")                                                           \
    for (int kk = 0; kk < 4; kk++) {                                            \
      int R = cd * 16 + l16;                                                    \
      int G = kk * 4 + quad;                                                    \
      bf16x8 kf = *(const bf16x8*)&ktc[R * 128 + (((G ^ R) & 7) | (G & 8)) * 8];\
      sacc[0] = __builtin_amdgcn_mfma_f32_16x16x32_bf16(qf[0][kk], kf, sacc[0], 0, 0, 0); \
      sacc[1] = __builtin_amdgcn_mfma_f32_16x16x32_bf16(qf[1][kk], kf, sacc[1], 0, 0, 0); \
    }                                                                           \
    _Pragma("unroll")                                                           \
    for (int i = 0; i < 2; i++)                                                 \
      _Pragma("unroll")                                                         \
      for (int r = 0; r < 4; r++)                                               \
        pt[(g * 32 + i * 16 + quad * 4 + r) * 72 + cd * 16 + l16] =             \
            to_bf16(__expf(sacc[i][r] * scale));                                \
  } while (0)

  // ---- prologue: stage K(0),V(0),K(1); compute S(0) -> pt ----
  STAGE_K(0);
  STAGE_V(0);
  STAGE_K(1);
  asm volatile("s_waitcnt vmcnt(2)" ::: "memory");   // K(0), V(0) landed; K(1) in flight
  __builtin_amdgcn_s_barrier();
  asm volatile("" ::: "memory");
  S_PHASE(0);
  asm volatile("s_waitcnt lgkmcnt(0)" ::: "memory");
  __builtin_amdgcn_s_barrier();                      // pt(0) ready
  asm volatile("" ::: "memory");

  for (int t = 0; t < 64; ++t) {
    // ---- load pf(t) into registers, then free pt for S(t+1) ----
    bf16x8 pf[2][2];
#pragma unroll
    for (int kk = 0; kk < 2; kk++)
#pragma unroll
      for (int i = 0; i < 2; i++)
        pf[kk][i] = *(const bf16x8*)&pt[(g * 32 + i * 16 + l16) * 72 + kk * 32 + quad * 8];
    asm volatile("s_waitcnt lgkmcnt(0)" ::: "memory");
    __builtin_amdgcn_s_barrier();        // all waves hold pf(t); pt free
    asm volatile("" ::: "memory");

    // ---- stage ahead: K(t+2) into buf t%2, V(t+1) into buf (t+1)%2 ----
    if (t < 62) STAGE_K(t & 1);
    if (t < 63) STAGE_V((t + 1) & 1);
    if (t < 62)      asm volatile("s_waitcnt vmcnt(4)" ::: "memory");  // K(t+1),V(t) landed
    else if (t == 62) asm volatile("s_waitcnt vmcnt(2)" ::: "memory");
    else              asm volatile("s_waitcnt vmcnt(0)" ::: "memory");

    // ---- merged phase: S(t+1) || PV(t) ----
    if (t < 63) {
      // S(t+1): kt buf (t+1)%2 -> sacc -> exp -> pt   (independent of PV below)
      const bf16* ktc = kt[(t + 1) & 1];
      f32x4 sacc[2] = {};
#pragma unroll
      for (int kk = 0; kk < 4; kk++) {
        int R = cd * 16 + l16;
        int G = kk * 4 + quad;
        bf16x8 kf = *(const bf16x8*)&ktc[R * 128 + (((G ^ R) & 7) | (G & 8)) * 8];
        sacc[0] = __builtin_amdgcn_mfma_f32_16x16x32_bf16(qf[0][kk], kf, sacc[0], 0, 0, 0);
        sacc[1] = __builtin_amdgcn_mfma_f32_16x16x32_bf16(qf[1][kk], kf, sacc[1], 0, 0, 0);
      }
      // PV(t): vt buf t%2, pf regs
      const bf16* vtc = vt[t & 1];
#pragma unroll
      for (int kk = 0; kk < 2; kk++) {
#pragma unroll
        for (int c = 0; c < 2; c++) {
          int R = cd * 32 + c * 16 + l16;
          int G = kk * 4 + quad;
          bf16x8 vf = *(const bf16x8*)&vtc[R * 64 + ((G ^ R) & 7) * 8];
#pragma unroll
          for (int i = 0; i < 2; i++)
            oacc[i][c] = __builtin_amdgcn_mfma_f32_16x16x32_bf16(pf[kk][i], vf, oacc[i][c], 0, 0, 0);
        }
        if (cd == 3) {
#pragma unroll
          for (int i = 0; i < 2; i++)
            oL[i] = __builtin_amdgcn_mfma_f32_16x16x32_bf16(pf[kk][i], onesf, oL[i], 0, 0, 0);
        }
      }
      // exp(t+1) + pt write (trails the S MFMAs)
#pragma unroll
      for (int i = 0; i < 2; i++)
#pragma unroll
        for (int r = 0; r < 4; r++)
          pt[(g * 32 + i * 16 + quad * 4 + r) * 72 + cd * 16 + l16] =
              to_bf16(__expf(sacc[i][r] * scale));
    } else {
      // last iter: PV(63) only
      const bf16* vtc = vt[t & 1];
#pragma unroll
      for (int kk = 0; kk < 2; kk++) {
#pragma unroll
        for (int c = 0; c < 2; c++) {
          int R = cd * 32 + c * 16 + l16;
          int G = kk * 4 + quad;
          bf16x8 vf = *(const bf16x8*)&vtc[R * 64 + ((G ^ R) & 7) * 8];
#pragma unroll
          for (int i = 0; i < 2; i++)
            oacc[i][c] = __builtin_amdgcn_mfma_f32_16x16x32_bf16(pf[kk][i], vf, oacc[i][c], 0, 0, 0);
        }
        if (cd == 3) {
#pragma unroll
          for (int i = 0; i < 2; i++)
            oL[i] = __builtin_amdgcn_mfma_f32_16x16x32_bf16(pf[kk][i], onesf, oL[i], 0, 0, 0);
        }
      }
    }
    asm volatile("s_waitcnt lgkmcnt(0)" ::: "memory");   // pt(t+1) writes visible
    __builtin_amdgcn_s_barrier();        // pt(t+1) ready; buffers rotate
    asm volatile("" ::: "memory");
  }
#undef STAGE_K
#undef STAGE_V
#undef S_PHASE

  // L at lanes l16==0 of cd==3 waves (C-layout col 0)
  if (cd == 3 && l16 == 0) {
#pragma unroll
    for (int i = 0; i < 2; i++)
#pragma unroll
      for (int r = 0; r < 4; r++) Lrow[g * 32 + i * 16 + quad * 4 + r] = oL[i][r];
  }
  __syncthreads();

  // normalize + write x[n][head*256 + dvh*128 + dv]
#pragma unroll
  for (int i = 0; i < 2; i++)
#pragma unroll
    for (int c = 0; c < 2; c++)
#pragma unroll
      for (int r = 0; r < 4; r++) {
        int row = g * 32 + i * 16 + quad * 4 + r;
        float v = oacc[i][c][r] / Lrow[row];
        x[(size_t)(q0 + row) * 1024 + head * 256 + dvh * 128 + cd * 32 + c * 16 + l16] =
            to_bf16(v);
      }
}

// ---------------- launch ----------------
extern "C" void kernel_launch(void* const* d_in, const int* in_sizes, int n_in,
                              void* d_out, int out_size, void* d_ws, size_t ws_size,
                              hipStream_t stream) {
  const float* Q  = (const float*)d_in[0];
  const float* Km = (const float*)d_in[1];
  const float* V  = (const float*)d_in[2];
  const float* Wq = (const float*)d_in[3];
  const float* Wk = (const float*)d_in[4];
  const float* Wv = (const float*)d_in[5];
  const float* Wo = (const float*)d_in[6];
  float* out = (float*)d_out;

  bf16* ws  = (bf16*)d_ws;
  bf16* Qb  = ws;                 // 4096x512   (Qb,Kb,Vb contiguous)
  bf16* Kb  = Qb + 2097152;
  bf16* Vb  = Kb + 2097152;
  bf16* Wqt = Vb + 2097152;       // 512x512  (Wqt,Wkt,Wvt contiguous)
  bf16* Wkt = Wqt + 262144;
  bf16* Wvt = Wkt + 262144;       // 1024x512 (Bt)
  bf16* Wob = Wvt + 524288;       // 512x1024 (Bt = Wo as-is)
  bf16* qb  = Wob + 524288;       // 4096x512   (qb,kb contiguous)
  bf16* kb  = qb + 2097152;
  bf16* vT  = kb + 2097152;       // 1024x4096  (written directly by proj z==2)
  bf16* x   = vT + 4194304;       // 4096x1024

  prep<<<3712, 256, 0, stream>>>(Q, Km, V, Wo, Qb, Kb, Vb, Wob, Wq, Wk, Wv, Wqt, Wkt, Wvt);

  proj_gemm<<<512, 256, 0, stream>>>(Qb, Wqt, qb, vT);

  attn<<<512, 512, 0, stream>>>(qb, kb, vT, x);

  out_gemm<<<dim3(32, 8), 256, 0, stream>>>(x, Wob, out);
}